// Round 3
// baseline (1126.100 us; speedup 1.0000x reference)
//
#include <hip/hip_runtime.h>
#include <hip/hip_bf16.h>
#include <stddef.h>

// Problem constants (fixed by harness)
constexpr int N    = 100000;
constexpr int E    = 1600000;
constexpr int F_IN = 128;
constexpr int H    = 64;
constexpr int C    = 16;
constexpr float BN_EPS = 1e-5f;

#define DEV __device__ __forceinline__

DEV float elu_f(float x) { return x > 0.f ? x : (expf(x) - 1.f); }

// ---------------------------------------------------------------------------
// CSR build: histogram -> scan -> fill  (built once per launch, reused by
// both GIN layers)
// ---------------------------------------------------------------------------
__global__ void k_hist(const int* __restrict__ dst, int* __restrict__ counts) {
    int i = blockIdx.x * blockDim.x + threadIdx.x;
    if (i < E) atomicAdd(&counts[dst[i]], 1);
}

// Block-level inclusive scan over 1024-elt tiles.
__global__ __launch_bounds__(1024) void k_scan1(const int* __restrict__ counts,
                                                int* __restrict__ incl,
                                                int* __restrict__ bsum) {
    __shared__ int lds[1024];
    int t = threadIdx.x;
    int g = blockIdx.x * 1024 + t;
    int v = (g < N) ? counts[g] : 0;
    lds[t] = v;
    __syncthreads();
    for (int off = 1; off < 1024; off <<= 1) {
        int add = (t >= off) ? lds[t - off] : 0;
        __syncthreads();
        lds[t] += add;
        __syncthreads();
    }
    if (g < N) incl[g] = lds[t];
    if (t == 1023) bsum[blockIdx.x] = lds[t];
}

// Exclusive scan of the (<=128) block sums, single block.
__global__ void k_scan2(int* __restrict__ bsum) {
    __shared__ int lds[128];
    int t = threadIdx.x;                  // 128 threads
    constexpr int NB = (N + 1023) / 1024; // 98
    int v = (t < NB) ? bsum[t] : 0;
    lds[t] = v;
    __syncthreads();
    for (int off = 1; off < 128; off <<= 1) {
        int add = (t >= off) ? lds[t - off] : 0;
        __syncthreads();
        lds[t] += add;
        __syncthreads();
    }
    if (t < NB) bsum[t] = lds[t] - v;     // exclusive
}

__global__ void k_scan3(const int* __restrict__ counts, const int* __restrict__ incl,
                        const int* __restrict__ bsum, int* __restrict__ row_ptr,
                        int* __restrict__ cursor) {
    int i = blockIdx.x * blockDim.x + threadIdx.x;
    if (i < N) {
        int excl = incl[i] - counts[i] + bsum[i >> 10];
        row_ptr[i] = excl;
        cursor[i]  = excl;
    }
    if (i == 0) row_ptr[N] = E;
}

__global__ void k_fill(const int* __restrict__ src, const int* __restrict__ dst,
                       int* __restrict__ cursor, int* __restrict__ csr_src) {
    int i = blockIdx.x * blockDim.x + threadIdx.x;
    if (i < E) {
        int pos = atomicAdd(&cursor[dst[i]], 1);
        csr_src[pos] = src[i];
    }
}

// ---------------------------------------------------------------------------
// Linear: out[N,64] = act( in'[N,K] @ W[K,64] (+bias) ), in' = optional BN+ELU
//
// lane = node row (one full output row per lane, acc[64] in VGPRs).
// W / bias / scale / shift accesses are wave-uniform -> scalar cache (s_load),
// so the vector pipes see ~1 global float4 load per 256 FMAs. No LDS.
// ---------------------------------------------------------------------------
template <int K, bool BN_IN, bool ELU_OUT, bool BIAS>
__global__ __launch_bounds__(256) void k_linear(const float* __restrict__ in,
                                                const float* __restrict__ W,
                                                const float* __restrict__ bias,
                                                const float* __restrict__ scale,
                                                const float* __restrict__ shift,
                                                float* __restrict__ out) {
    const int lane = threadIdx.x & 63;
    const int wid  = (blockIdx.x * blockDim.x + threadIdx.x) >> 6;
    const int row  = wid * 64 + lane;
    if (row >= N) return;

    float acc[64];
#pragma unroll
    for (int f = 0; f < 64; ++f) acc[f] = BIAS ? bias[f] : 0.f;  // uniform s_load

    const float* xr = in + (size_t)row * K;

#pragma unroll 2
    for (int k4 = 0; k4 < K / 4; ++k4) {
        float4 xv = *reinterpret_cast<const float4*>(xr + k4 * 4);
        if (BN_IN) {
            const int c = k4 * 4;  // uniform
            xv.x = elu_f(xv.x * scale[c + 0] + shift[c + 0]);
            xv.y = elu_f(xv.y * scale[c + 1] + shift[c + 1]);
            xv.z = elu_f(xv.z * scale[c + 2] + shift[c + 2]);
            xv.w = elu_f(xv.w * scale[c + 3] + shift[c + 3]);
        }
#pragma unroll
        for (int j = 0; j < 4; ++j) {
            const float xk = (j == 0) ? xv.x : (j == 1) ? xv.y : (j == 2) ? xv.z : xv.w;
            const float* Wk = W + (size_t)(k4 * 4 + j) * 64;  // uniform row
#pragma unroll
            for (int f = 0; f < 64; ++f) acc[f] = fmaf(xk, Wk[f], acc[f]);
        }
    }

    float* orow = out + (size_t)row * 64;
#pragma unroll
    for (int f4 = 0; f4 < 16; ++f4) {
        float4 v;
        v.x = ELU_OUT ? elu_f(acc[f4 * 4 + 0]) : acc[f4 * 4 + 0];
        v.y = ELU_OUT ? elu_f(acc[f4 * 4 + 1]) : acc[f4 * 4 + 1];
        v.z = ELU_OUT ? elu_f(acc[f4 * 4 + 2]) : acc[f4 * 4 + 2];
        v.w = ELU_OUT ? elu_f(acc[f4 * 4 + 3]) : acc[f4 * 4 + 3];
        *reinterpret_cast<float4*>(orow + f4 * 4) = v;
    }
}

// ---------------------------------------------------------------------------
// Aggregation: z[n][f] = y[n][f] + sum_{s in CSR(n)} y[s][f] + bias[f]
// One wave per node, lane = feature.
//   - All (<=64) neighbor indices fetched in ONE parallel vector load,
//     then broadcast from registers via __shfl -> no index-load latency
//     on the critical path.
//   - Gather loop unrolled x4 -> 4 independent 256B gathers in flight.
//   - deg is wave-uniform -> all branches uniform (no divergence).
// ---------------------------------------------------------------------------
__global__ __launch_bounds__(256) void k_agg(const float* __restrict__ y,
                                             const int* __restrict__ row_ptr,
                                             const int* __restrict__ csr_src,
                                             const float* __restrict__ bias,
                                             float* __restrict__ z) {
    int wid  = (blockIdx.x * blockDim.x + threadIdx.x) >> 6;
    int lane = threadIdx.x & 63;
    if (wid >= N) return;
    int beg = __builtin_amdgcn_readfirstlane(row_ptr[wid]);
    int end = __builtin_amdgcn_readfirstlane(row_ptr[wid + 1]);
    int deg = end - beg;

    // one coalesced load grabs all neighbor indices (deg <= 64 ~ always)
    int myidx = (lane < deg) ? csr_src[beg + lane] : 0;

    float acc = y[(size_t)wid * 64 + lane];
    int d64 = deg < 64 ? deg : 64;
    int k = 0;
    for (; k + 4 <= d64; k += 4) {
        int s0 = __shfl(myidx, k + 0);
        int s1 = __shfl(myidx, k + 1);
        int s2 = __shfl(myidx, k + 2);
        int s3 = __shfl(myidx, k + 3);
        float v0 = y[(size_t)s0 * 64 + lane];
        float v1 = y[(size_t)s1 * 64 + lane];
        float v2 = y[(size_t)s2 * 64 + lane];
        float v3 = y[(size_t)s3 * 64 + lane];
        acc += v0; acc += v1; acc += v2; acc += v3;
    }
    for (; k < d64; ++k) {
        int s = __shfl(myidx, k);
        acc += y[(size_t)s * 64 + lane];
    }
    // rare tail: degree > 64
    for (int kk = beg + 64; kk < end; ++kk) {
        int s = csr_src[kk];  // wave-uniform
        acc += y[(size_t)s * 64 + lane];
    }
    z[(size_t)wid * 64 + lane] = acc + bias[lane];
}

// ---------------------------------------------------------------------------
// BN stats: per-block partial sums/sumsq per feature -> finalize scale/shift
// ---------------------------------------------------------------------------
__global__ __launch_bounds__(256) void k_stats1(const float* __restrict__ z,
                                                float* __restrict__ part) {
    __shared__ float s1[256], s2[256];
    int t = threadIdx.x;
    int f = t & 63, g = t >> 6;
    float sum = 0.f, sq = 0.f;
    for (int r = blockIdx.x * 4 + g; r < N; r += gridDim.x * 4) {
        float v = z[(size_t)r * 64 + f];
        sum += v;
        sq  += v * v;
    }
    s1[t] = sum; s2[t] = sq;
    __syncthreads();
    if (t < 128) { s1[t] += s1[t + 128]; s2[t] += s2[t + 128]; }
    __syncthreads();
    if (t < 64) {
        part[blockIdx.x * 128 + t]      = s1[t] + s1[t + 64];
        part[blockIdx.x * 128 + 64 + t] = s2[t] + s2[t + 64];
    }
}

__global__ void k_stats2(const float* __restrict__ part, const float* __restrict__ g,
                         const float* __restrict__ be, float* __restrict__ scale,
                         float* __restrict__ shift) {
    __shared__ float lds[128];
    int t = threadIdx.x;  // 128 threads
    float s = 0.f;
    for (int b = 0; b < 256; ++b) s += part[b * 128 + t];
    lds[t] = s;
    __syncthreads();
    if (t < 64) {
        float mu   = lds[t] * (1.f / N);
        float var  = lds[64 + t] * (1.f / N) - mu * mu;
        float rstd = rsqrtf(var + BN_EPS);
        float sc   = rstd * g[t];
        scale[t] = sc;
        shift[t] = be[t] - mu * sc;
    }
}

// ---------------------------------------------------------------------------
// Head: out = relu([h1,h2] @ Wl1 + bl1) @ Wl2 + bl2
// Same lane=row scheme; hidden activations stay in registers between the two
// matmuls (no LDS round-trip).
// ---------------------------------------------------------------------------
__global__ __launch_bounds__(256) void k_final(const float* __restrict__ h1,
                                               const float* __restrict__ h2,
                                               const float* __restrict__ Wl1,
                                               const float* __restrict__ bl1,
                                               const float* __restrict__ Wl2,
                                               const float* __restrict__ bl2,
                                               float* __restrict__ out) {
    const int lane = threadIdx.x & 63;
    const int wid  = (blockIdx.x * blockDim.x + threadIdx.x) >> 6;
    const int row  = wid * 64 + lane;
    if (row >= N) return;

    float acc[64];
#pragma unroll
    for (int f = 0; f < 64; ++f) acc[f] = bl1[f];

    // k in [0,128): first 64 from h1, next 64 from h2
#pragma unroll 1
    for (int half = 0; half < 2; ++half) {
        const float* xr = (half == 0 ? h1 : h2) + (size_t)row * 64;
        const float* Wh = Wl1 + (size_t)half * 64 * 64;
#pragma unroll 2
        for (int k4 = 0; k4 < 16; ++k4) {
            float4 xv = *reinterpret_cast<const float4*>(xr + k4 * 4);
#pragma unroll
            for (int j = 0; j < 4; ++j) {
                const float xk = (j == 0) ? xv.x : (j == 1) ? xv.y : (j == 2) ? xv.z : xv.w;
                const float* Wk = Wh + (size_t)(k4 * 4 + j) * 64;
#pragma unroll
                for (int f = 0; f < 64; ++f) acc[f] = fmaf(xk, Wk[f], acc[f]);
            }
        }
    }

    // relu -> second matmul (64 -> 16), all in registers
    float acc2[16];
#pragma unroll
    for (int c = 0; c < 16; ++c) acc2[c] = bl2[c];
#pragma unroll 4
    for (int k = 0; k < 64; ++k) {
        float tk = fmaxf(acc[k], 0.f);
        const float* Wk = Wl2 + (size_t)k * 16;  // uniform
#pragma unroll
        for (int c = 0; c < 16; ++c) acc2[c] = fmaf(tk, Wk[c], acc2[c]);
    }

    float* orow = out + (size_t)row * 16;
#pragma unroll
    for (int c4 = 0; c4 < 4; ++c4) {
        float4 v;
        v.x = acc2[c4 * 4 + 0];
        v.y = acc2[c4 * 4 + 1];
        v.z = acc2[c4 * 4 + 2];
        v.w = acc2[c4 * 4 + 3];
        *reinterpret_cast<float4*>(orow + c4 * 4) = v;
    }
}

// ---------------------------------------------------------------------------
// Launch
// ---------------------------------------------------------------------------
extern "C" void kernel_launch(void* const* d_in, const int* in_sizes, int n_in,
                              void* d_out, int out_size, void* d_ws, size_t ws_size,
                              hipStream_t stream) {
    const float* x   = (const float*)d_in[0];
    const int*   ei  = (const int*)d_in[1];
    const int*   esrc = ei;       // edge_index[0]
    const int*   edst = ei + E;   // edge_index[1]
    const float* W1  = (const float*)d_in[2];
    const float* b1  = (const float*)d_in[3];
    const float* g1  = (const float*)d_in[4];
    const float* be1 = (const float*)d_in[5];
    const float* W2  = (const float*)d_in[6];
    const float* b2  = (const float*)d_in[7];
    const float* W3  = (const float*)d_in[8];
    const float* b3  = (const float*)d_in[9];
    const float* g2  = (const float*)d_in[10];
    const float* be2 = (const float*)d_in[11];
    const float* W4  = (const float*)d_in[12];
    const float* b4  = (const float*)d_in[13];
    const float* Wl1 = (const float*)d_in[14];
    const float* bl1 = (const float*)d_in[15];
    const float* Wl2 = (const float*)d_in[16];
    const float* bl2 = (const float*)d_in[17];
    float* out = (float*)d_out;

    // Workspace carve (aligned 256B)
    char* p = (char*)d_ws;
    auto carve = [&](size_t bytes) {
        void* r = (void*)p;
        p += (bytes + 255) & ~(size_t)255;
        return r;
    };
    constexpr size_t SROW = (size_t)N * H * sizeof(float);  // 25.6 MB
    float* y   = (float*)carve(SROW);
    float* z   = (float*)carve(SROW);
    float* h1  = (float*)carve(SROW);
    float* h2  = (float*)carve(SROW);
    int* counts  = (int*)carve((size_t)N * 4);
    int* incl    = (int*)carve((size_t)N * 4);
    int* bsum    = (int*)carve(128 * 4);
    int* row_ptr = (int*)carve((size_t)(N + 1) * 4);
    int* cursor  = (int*)carve((size_t)N * 4);
    int* csr     = (int*)carve((size_t)E * 4);
    float* part  = (float*)carve((size_t)256 * 128 * 4);
    float* scale = (float*)carve(64 * 4);
    float* shift = (float*)carve(64 * 4);
    (void)ws_size; (void)in_sizes; (void)n_in; (void)out_size;

    constexpr int EBLK   = (E + 255) / 256;         // 6250
    constexpr int SCAN_B = (N + 1023) / 1024;       // 98
    constexpr int LINB   = ((N + 63) / 64 + 3) / 4; // 391 blocks of 4 waves

    // CSR build (reused by both layers)
    hipMemsetAsync(counts, 0, (size_t)N * 4, stream);
    k_hist<<<EBLK, 256, 0, stream>>>(edst, counts);
    k_scan1<<<SCAN_B, 1024, 0, stream>>>(counts, incl, bsum);
    k_scan2<<<1, 128, 0, stream>>>(bsum);
    k_scan3<<<(N + 255) / 256, 256, 0, stream>>>(counts, incl, bsum, row_ptr, cursor);
    k_fill<<<EBLK, 256, 0, stream>>>(esrc, edst, cursor, csr);

    // Layer 1: y = x@W1 ; z = y + sum_src(y) + b1 ; stats ; h1 = elu(bnelu(z)@W2 + b2)
    k_linear<128, false, false, false><<<LINB, 256, 0, stream>>>(x, W1, nullptr, nullptr, nullptr, y);
    k_agg<<<N * 64 / 256, 256, 0, stream>>>(y, row_ptr, csr, b1, z);
    k_stats1<<<256, 256, 0, stream>>>(z, part);
    k_stats2<<<1, 128, 0, stream>>>(part, g1, be1, scale, shift);
    k_linear<64, true, true, true><<<LINB, 256, 0, stream>>>(z, W2, b2, scale, shift, h1);

    // Layer 2
    k_linear<64, false, false, false><<<LINB, 256, 0, stream>>>(h1, W3, nullptr, nullptr, nullptr, y);
    k_agg<<<N * 64 / 256, 256, 0, stream>>>(y, row_ptr, csr, b3, z);
    k_stats1<<<256, 256, 0, stream>>>(z, part);
    k_stats2<<<1, 128, 0, stream>>>(part, g2, be2, scale, shift);
    k_linear<64, true, true, true><<<LINB, 256, 0, stream>>>(z, W4, b4, scale, shift, h2);

    // Head
    k_final<<<LINB, 256, 0, stream>>>(h1, h2, Wl1, bl1, Wl2, bl2, out);
}

// Round 4
// 732.490 us; speedup vs baseline: 1.5374x; 1.5374x over previous
//
#include <hip/hip_runtime.h>
#include <hip/hip_bf16.h>
#include <stddef.h>

// Problem constants (fixed by harness)
constexpr int N    = 100000;
constexpr int E    = 1600000;
constexpr int F_IN = 128;
constexpr int H    = 64;
constexpr int C    = 16;
constexpr float BN_EPS = 1e-5f;

#define DEV __device__ __forceinline__

DEV float elu_f(float x) { return x > 0.f ? x : (expf(x) - 1.f); }

// ---------------------------------------------------------------------------
// CSR build: histogram -> scan -> fill  (built once per launch, reused by
// both GIN layers)
// ---------------------------------------------------------------------------
__global__ void k_hist(const int* __restrict__ dst, int* __restrict__ counts) {
    int i = blockIdx.x * blockDim.x + threadIdx.x;
    if (i < E) atomicAdd(&counts[dst[i]], 1);
}

// Block-level inclusive scan over 1024-elt tiles.
__global__ __launch_bounds__(1024) void k_scan1(const int* __restrict__ counts,
                                                int* __restrict__ incl,
                                                int* __restrict__ bsum) {
    __shared__ int lds[1024];
    int t = threadIdx.x;
    int g = blockIdx.x * 1024 + t;
    int v = (g < N) ? counts[g] : 0;
    lds[t] = v;
    __syncthreads();
    for (int off = 1; off < 1024; off <<= 1) {
        int add = (t >= off) ? lds[t - off] : 0;
        __syncthreads();
        lds[t] += add;
        __syncthreads();
    }
    if (g < N) incl[g] = lds[t];
    if (t == 1023) bsum[blockIdx.x] = lds[t];
}

// Exclusive scan of the (<=128) block sums, single block.
__global__ void k_scan2(int* __restrict__ bsum) {
    __shared__ int lds[128];
    int t = threadIdx.x;                  // 128 threads
    constexpr int NB = (N + 1023) / 1024; // 98
    int v = (t < NB) ? bsum[t] : 0;
    lds[t] = v;
    __syncthreads();
    for (int off = 1; off < 128; off <<= 1) {
        int add = (t >= off) ? lds[t - off] : 0;
        __syncthreads();
        lds[t] += add;
        __syncthreads();
    }
    if (t < NB) bsum[t] = lds[t] - v;     // exclusive
}

__global__ void k_scan3(const int* __restrict__ counts, const int* __restrict__ incl,
                        const int* __restrict__ bsum, int* __restrict__ row_ptr,
                        int* __restrict__ cursor) {
    int i = blockIdx.x * blockDim.x + threadIdx.x;
    if (i < N) {
        int excl = incl[i] - counts[i] + bsum[i >> 10];
        row_ptr[i] = excl;
        cursor[i]  = excl;
    }
    if (i == 0) row_ptr[N] = E;
}

__global__ void k_fill(const int* __restrict__ src, const int* __restrict__ dst,
                       int* __restrict__ cursor, int* __restrict__ csr_src) {
    int i = blockIdx.x * blockDim.x + threadIdx.x;
    if (i < E) {
        int pos = atomicAdd(&cursor[dst[i]], 1);
        csr_src[pos] = src[i];
    }
}

// ---------------------------------------------------------------------------
// Linear: out[N,64] = act( in'[N,K] @ W[K,64] (+bias) ), in' = optional BN+ELU
//
// lane = node row (one full output row per lane, acc[64] in VGPRs; every
// acc[] index is compile-time static -> stays in registers, rule #20).
// W rows are wave-uniform float4 loads (16 VMEM : 128 FMA per k4-step).
// ---------------------------------------------------------------------------
template <int K, bool BN_IN, bool ELU_OUT, bool BIAS>
__global__ __launch_bounds__(256) void k_linear(const float* __restrict__ in,
                                                const float* __restrict__ W,
                                                const float* __restrict__ bias,
                                                const float* __restrict__ scale,
                                                const float* __restrict__ shift,
                                                float* __restrict__ out) {
    const int lane = threadIdx.x & 63;
    const int wid  = (blockIdx.x * blockDim.x + threadIdx.x) >> 6;
    const int row  = wid * 64 + lane;
    if (row >= N) return;

    float acc[64];
#pragma unroll
    for (int f = 0; f < 64; ++f) acc[f] = BIAS ? bias[f] : 0.f;  // uniform

    const float* xr = in + (size_t)row * K;

#pragma unroll 2
    for (int k4 = 0; k4 < K / 4; ++k4) {
        float4 xv = *reinterpret_cast<const float4*>(xr + k4 * 4);
        if (BN_IN) {
            const int c = k4 * 4;  // uniform
            xv.x = elu_f(xv.x * scale[c + 0] + shift[c + 0]);
            xv.y = elu_f(xv.y * scale[c + 1] + shift[c + 1]);
            xv.z = elu_f(xv.z * scale[c + 2] + shift[c + 2]);
            xv.w = elu_f(xv.w * scale[c + 3] + shift[c + 3]);
        }
#pragma unroll
        for (int j = 0; j < 4; ++j) {
            const float xk = (j == 0) ? xv.x : (j == 1) ? xv.y : (j == 2) ? xv.z : xv.w;
            const float4* Wk = reinterpret_cast<const float4*>(W + (size_t)(k4 * 4 + j) * 64);
#pragma unroll
            for (int f4 = 0; f4 < 16; ++f4) {
                float4 w = Wk[f4];
                acc[f4 * 4 + 0] = fmaf(xk, w.x, acc[f4 * 4 + 0]);
                acc[f4 * 4 + 1] = fmaf(xk, w.y, acc[f4 * 4 + 1]);
                acc[f4 * 4 + 2] = fmaf(xk, w.z, acc[f4 * 4 + 2]);
                acc[f4 * 4 + 3] = fmaf(xk, w.w, acc[f4 * 4 + 3]);
            }
        }
    }

    float* orow = out + (size_t)row * 64;
#pragma unroll
    for (int f4 = 0; f4 < 16; ++f4) {
        float4 v;
        v.x = ELU_OUT ? elu_f(acc[f4 * 4 + 0]) : acc[f4 * 4 + 0];
        v.y = ELU_OUT ? elu_f(acc[f4 * 4 + 1]) : acc[f4 * 4 + 1];
        v.z = ELU_OUT ? elu_f(acc[f4 * 4 + 2]) : acc[f4 * 4 + 2];
        v.w = ELU_OUT ? elu_f(acc[f4 * 4 + 3]) : acc[f4 * 4 + 3];
        *reinterpret_cast<float4*>(orow + f4 * 4) = v;
    }
}

// ---------------------------------------------------------------------------
// Aggregation: z[n][f] = y[n][f] + sum_{s in CSR(n)} y[s][f] + bias[f]
// One wave per node, lane = feature. Neighbor indices fetched in one
// parallel load, broadcast from registers via __shfl; gather unrolled x4.
// ---------------------------------------------------------------------------
__global__ __launch_bounds__(256) void k_agg(const float* __restrict__ y,
                                             const int* __restrict__ row_ptr,
                                             const int* __restrict__ csr_src,
                                             const float* __restrict__ bias,
                                             float* __restrict__ z) {
    int wid  = (blockIdx.x * blockDim.x + threadIdx.x) >> 6;
    int lane = threadIdx.x & 63;
    if (wid >= N) return;
    int beg = __builtin_amdgcn_readfirstlane(row_ptr[wid]);
    int end = __builtin_amdgcn_readfirstlane(row_ptr[wid + 1]);
    int deg = end - beg;

    // one coalesced load grabs all neighbor indices (deg <= 64 ~ always)
    int myidx = (lane < deg) ? csr_src[beg + lane] : 0;

    float acc = y[(size_t)wid * 64 + lane];
    int d64 = deg < 64 ? deg : 64;
    int k = 0;
    for (; k + 4 <= d64; k += 4) {
        int s0 = __shfl(myidx, k + 0);
        int s1 = __shfl(myidx, k + 1);
        int s2 = __shfl(myidx, k + 2);
        int s3 = __shfl(myidx, k + 3);
        float v0 = y[(size_t)s0 * 64 + lane];
        float v1 = y[(size_t)s1 * 64 + lane];
        float v2 = y[(size_t)s2 * 64 + lane];
        float v3 = y[(size_t)s3 * 64 + lane];
        acc += v0; acc += v1; acc += v2; acc += v3;
    }
    for (; k < d64; ++k) {
        int s = __shfl(myidx, k);
        acc += y[(size_t)s * 64 + lane];
    }
    // rare tail: degree > 64
    for (int kk = beg + 64; kk < end; ++kk) {
        int s = csr_src[kk];  // wave-uniform
        acc += y[(size_t)s * 64 + lane];
    }
    z[(size_t)wid * 64 + lane] = acc + bias[lane];
}

// ---------------------------------------------------------------------------
// BN stats: per-block partial sums/sumsq per feature -> finalize scale/shift
// ---------------------------------------------------------------------------
__global__ __launch_bounds__(256) void k_stats1(const float* __restrict__ z,
                                                float* __restrict__ part) {
    __shared__ float s1[256], s2[256];
    int t = threadIdx.x;
    int f = t & 63, g = t >> 6;
    float sum = 0.f, sq = 0.f;
    for (int r = blockIdx.x * 4 + g; r < N; r += gridDim.x * 4) {
        float v = z[(size_t)r * 64 + f];
        sum += v;
        sq  += v * v;
    }
    s1[t] = sum; s2[t] = sq;
    __syncthreads();
    if (t < 128) { s1[t] += s1[t + 128]; s2[t] += s2[t + 128]; }
    __syncthreads();
    if (t < 64) {
        part[blockIdx.x * 128 + t]      = s1[t] + s1[t + 64];
        part[blockIdx.x * 128 + 64 + t] = s2[t] + s2[t + 64];
    }
}

__global__ void k_stats2(const float* __restrict__ part, const float* __restrict__ g,
                         const float* __restrict__ be, float* __restrict__ scale,
                         float* __restrict__ shift) {
    __shared__ float lds[128];
    int t = threadIdx.x;  // 128 threads
    float s = 0.f;
    for (int b = 0; b < 256; ++b) s += part[b * 128 + t];
    lds[t] = s;
    __syncthreads();
    if (t < 64) {
        float mu   = lds[t] * (1.f / N);
        float var  = lds[64 + t] * (1.f / N) - mu * mu;
        float rstd = rsqrtf(var + BN_EPS);
        float sc   = rstd * g[t];
        scale[t] = sc;
        shift[t] = be[t] - mu * sc;
    }
}

// ---------------------------------------------------------------------------
// Head: out = relu([h1,h2] @ Wl1 + bl1) @ Wl2 + bl2
// lane = row; hidden activations stay in registers between the two matmuls.
// ALL acc[] indices are compile-time static (full unroll) -> no scratch.
// ---------------------------------------------------------------------------
__global__ __launch_bounds__(256) void k_final(const float* __restrict__ h1,
                                               const float* __restrict__ h2,
                                               const float* __restrict__ Wl1,
                                               const float* __restrict__ bl1,
                                               const float* __restrict__ Wl2,
                                               const float* __restrict__ bl2,
                                               float* __restrict__ out) {
    const int lane = threadIdx.x & 63;
    const int wid  = (blockIdx.x * blockDim.x + threadIdx.x) >> 6;
    const int row  = wid * 64 + lane;
    if (row >= N) return;

    float acc[64];
#pragma unroll
    for (int f = 0; f < 64; ++f) acc[f] = bl1[f];

    // k in [0,128): first 64 from h1, next 64 from h2
#pragma unroll 1
    for (int half = 0; half < 2; ++half) {
        const float* xr = (half == 0 ? h1 : h2) + (size_t)row * 64;
        const float* Wh = Wl1 + (size_t)half * 64 * 64;
#pragma unroll 2
        for (int k4 = 0; k4 < 16; ++k4) {
            float4 xv = *reinterpret_cast<const float4*>(xr + k4 * 4);
#pragma unroll
            for (int j = 0; j < 4; ++j) {
                const float xk = (j == 0) ? xv.x : (j == 1) ? xv.y : (j == 2) ? xv.z : xv.w;
                const float4* Wk = reinterpret_cast<const float4*>(Wh + (size_t)(k4 * 4 + j) * 64);
#pragma unroll
                for (int f4 = 0; f4 < 16; ++f4) {
                    float4 w = Wk[f4];
                    acc[f4 * 4 + 0] = fmaf(xk, w.x, acc[f4 * 4 + 0]);
                    acc[f4 * 4 + 1] = fmaf(xk, w.y, acc[f4 * 4 + 1]);
                    acc[f4 * 4 + 2] = fmaf(xk, w.z, acc[f4 * 4 + 2]);
                    acc[f4 * 4 + 3] = fmaf(xk, w.w, acc[f4 * 4 + 3]);
                }
            }
        }
    }

    // relu -> second matmul (64 -> 16), FULLY unrolled so acc[k] is static
    float acc2[16];
#pragma unroll
    for (int c = 0; c < 16; ++c) acc2[c] = bl2[c];
#pragma unroll
    for (int k = 0; k < 64; ++k) {
        float tk = fmaxf(acc[k], 0.f);
        const float4* Wk = reinterpret_cast<const float4*>(Wl2 + (size_t)k * 16);
#pragma unroll
        for (int c4 = 0; c4 < 4; ++c4) {
            float4 w = Wk[c4];
            acc2[c4 * 4 + 0] = fmaf(tk, w.x, acc2[c4 * 4 + 0]);
            acc2[c4 * 4 + 1] = fmaf(tk, w.y, acc2[c4 * 4 + 1]);
            acc2[c4 * 4 + 2] = fmaf(tk, w.z, acc2[c4 * 4 + 2]);
            acc2[c4 * 4 + 3] = fmaf(tk, w.w, acc2[c4 * 4 + 3]);
        }
    }

    float* orow = out + (size_t)row * 16;
#pragma unroll
    for (int c4 = 0; c4 < 4; ++c4) {
        float4 v;
        v.x = acc2[c4 * 4 + 0];
        v.y = acc2[c4 * 4 + 1];
        v.z = acc2[c4 * 4 + 2];
        v.w = acc2[c4 * 4 + 3];
        *reinterpret_cast<float4*>(orow + c4 * 4) = v;
    }
}

// ---------------------------------------------------------------------------
// Launch
// ---------------------------------------------------------------------------
extern "C" void kernel_launch(void* const* d_in, const int* in_sizes, int n_in,
                              void* d_out, int out_size, void* d_ws, size_t ws_size,
                              hipStream_t stream) {
    const float* x   = (const float*)d_in[0];
    const int*   ei  = (const int*)d_in[1];
    const int*   esrc = ei;       // edge_index[0]
    const int*   edst = ei + E;   // edge_index[1]
    const float* W1  = (const float*)d_in[2];
    const float* b1  = (const float*)d_in[3];
    const float* g1  = (const float*)d_in[4];
    const float* be1 = (const float*)d_in[5];
    const float* W2  = (const float*)d_in[6];
    const float* b2  = (const float*)d_in[7];
    const float* W3  = (const float*)d_in[8];
    const float* b3  = (const float*)d_in[9];
    const float* g2  = (const float*)d_in[10];
    const float* be2 = (const float*)d_in[11];
    const float* W4  = (const float*)d_in[12];
    const float* b4  = (const float*)d_in[13];
    const float* Wl1 = (const float*)d_in[14];
    const float* bl1 = (const float*)d_in[15];
    const float* Wl2 = (const float*)d_in[16];
    const float* bl2 = (const float*)d_in[17];
    float* out = (float*)d_out;

    // Workspace carve (aligned 256B)
    char* p = (char*)d_ws;
    auto carve = [&](size_t bytes) {
        void* r = (void*)p;
        p += (bytes + 255) & ~(size_t)255;
        return r;
    };
    constexpr size_t SROW = (size_t)N * H * sizeof(float);  // 25.6 MB
    float* y   = (float*)carve(SROW);
    float* z   = (float*)carve(SROW);
    float* h1  = (float*)carve(SROW);
    float* h2  = (float*)carve(SROW);
    int* counts  = (int*)carve((size_t)N * 4);
    int* incl    = (int*)carve((size_t)N * 4);
    int* bsum    = (int*)carve(128 * 4);
    int* row_ptr = (int*)carve((size_t)(N + 1) * 4);
    int* cursor  = (int*)carve((size_t)N * 4);
    int* csr     = (int*)carve((size_t)E * 4);
    float* part  = (float*)carve((size_t)256 * 128 * 4);
    float* scale = (float*)carve(64 * 4);
    float* shift = (float*)carve(64 * 4);
    (void)ws_size; (void)in_sizes; (void)n_in; (void)out_size;

    constexpr int EBLK   = (E + 255) / 256;         // 6250
    constexpr int SCAN_B = (N + 1023) / 1024;       // 98
    constexpr int LINB   = ((N + 63) / 64 + 3) / 4; // 391 blocks of 4 waves

    // CSR build (reused by both layers)
    hipMemsetAsync(counts, 0, (size_t)N * 4, stream);
    k_hist<<<EBLK, 256, 0, stream>>>(edst, counts);
    k_scan1<<<SCAN_B, 1024, 0, stream>>>(counts, incl, bsum);
    k_scan2<<<1, 128, 0, stream>>>(bsum);
    k_scan3<<<(N + 255) / 256, 256, 0, stream>>>(counts, incl, bsum, row_ptr, cursor);
    k_fill<<<EBLK, 256, 0, stream>>>(esrc, edst, cursor, csr);

    // Layer 1: y = x@W1 ; z = y + sum_src(y) + b1 ; stats ; h1 = elu(bnelu(z)@W2 + b2)
    k_linear<128, false, false, false><<<LINB, 256, 0, stream>>>(x, W1, nullptr, nullptr, nullptr, y);
    k_agg<<<N * 64 / 256, 256, 0, stream>>>(y, row_ptr, csr, b1, z);
    k_stats1<<<256, 256, 0, stream>>>(z, part);
    k_stats2<<<1, 128, 0, stream>>>(part, g1, be1, scale, shift);
    k_linear<64, true, true, true><<<LINB, 256, 0, stream>>>(z, W2, b2, scale, shift, h1);

    // Layer 2
    k_linear<64, false, false, false><<<LINB, 256, 0, stream>>>(h1, W3, nullptr, nullptr, nullptr, y);
    k_agg<<<N * 64 / 256, 256, 0, stream>>>(y, row_ptr, csr, b3, z);
    k_stats1<<<256, 256, 0, stream>>>(z, part);
    k_stats2<<<1, 128, 0, stream>>>(part, g2, be2, scale, shift);
    k_linear<64, true, true, true><<<LINB, 256, 0, stream>>>(z, W4, b4, scale, shift, h2);

    // Head
    k_final<<<LINB, 256, 0, stream>>>(h1, h2, Wl1, bl1, Wl2, bl2, out);
}